// Round 3
// baseline (229.337 us; speedup 1.0000x reference)
//
#include <hip/hip_runtime.h>

#define PENALTY_N 0.1f
#define CP 20000         // nodes per partition -> 80 KB LDS -> 2 blocks/CU
#define MAX_BPP 102      // cap: P*MAX_BPP = 510 blocks ~= 2/CU
#define ABLK 1024        // threads per block, partition kernel

// ---------------------------------------------------------------------------
// Kernel A: partitioned scatter with LDS privatization.
// Block = (partition p, edge-slice b).  LDS holds partial sums for nodes
// [p*CP, p*CP+CP).  Scans its slice of ALL edges; endpoints in range get an
// LDS float atomic.  Flush = plain stores to private scratch (no global
// atomics).  80 KB LDS + <=64 VGPR (launch_bounds 1024,8) => 2 blocks/CU.
// ---------------------------------------------------------------------------
__global__ __launch_bounds__(ABLK, 8) void part_scatter_kernel(
    const int* __restrict__ src_idx,
    const int* __restrict__ dst_idx,
    const float* __restrict__ w,
    const float* __restrict__ traffic,
    float* __restrict__ scratch,   // [P][Bpp][CP]
    float* __restrict__ out_scalar,
    int nE, int nN, int Bpp) {
    __shared__ float hist[CP];

    const int p = blockIdx.x / Bpp;    // partition
    const int b = blockIdx.x % Bpp;    // edge slice
    const int lo = p * CP;
    const unsigned csz = (unsigned)min(CP, nN - lo);
    const int tid = threadIdx.x;

    if (blockIdx.x == 0 && tid == 0) *out_scalar = 0.0f;

    for (int i = tid; i < CP; i += ABLK) hist[i] = 0.0f;
    __syncthreads();

    const int nvec = nE >> 2;
    const int4* __restrict__ src4 = (const int4*)src_idx;
    const int4* __restrict__ dst4 = (const int4*)dst_idx;
    const float4* __restrict__ w4 = (const float4*)w;
    const int stride = Bpp * ABLK;

    for (int v = b * ABLK + tid; v < nvec; v += stride) {
        int4 s = src4[v];
        int4 d = dst4[v];
        float4 ww = w4[v];

        #pragma unroll
        for (int k = 0; k < 4; ++k) {
            int si = (&s.x)[k];
            int di = (&d.x)[k];
            unsigned so = (unsigned)(si - lo);
            unsigned doo = (unsigned)(di - lo);
            bool inS = so < csz;
            bool inD = doo < csz;
            if (inS || inD) {
                float t = fabsf(traffic[si] - traffic[di]) * (PENALTY_N * (&ww.x)[k]);
                if (inS) atomicAdd(&hist[so], -t);
                if (inD) atomicAdd(&hist[doo], t);
            }
        }
    }
    // scalar tail (nE % 4)
    for (int e = (nvec << 2) + b * ABLK + tid; e < nE; e += stride) {
        int si = src_idx[e];
        int di = dst_idx[e];
        unsigned so = (unsigned)(si - lo);
        unsigned doo = (unsigned)(di - lo);
        bool inS = so < csz;
        bool inD = doo < csz;
        if (inS || inD) {
            float t = fabsf(traffic[si] - traffic[di]) * (PENALTY_N * w[e]);
            if (inS) atomicAdd(&hist[so], -t);
            if (inD) atomicAdd(&hist[doo], t);
        }
    }

    __syncthreads();
    float* dst = scratch + (size_t)blockIdx.x * CP;
    for (int i = tid; i < CP; i += ABLK) dst[i] = hist[i];
}

// ---------------------------------------------------------------------------
// Kernel B: per-node sum of the Bpp private copies + base traffic; writes
// new_traffic and fuses the service-efficiency reduction.
// 8 loads in flight (4 independent accumulators) to break the latency chain.
// ---------------------------------------------------------------------------
__global__ __launch_bounds__(256) void part_reduce_kernel(
    const float* __restrict__ scratch,
    const float* __restrict__ traffic,
    const float* __restrict__ yield_rate,
    const float* __restrict__ cost,
    float* __restrict__ out,        // [nN] new_traffic, out[nN] scalar
    int nN, int Bpp) {
    const int tid = blockIdx.x * blockDim.x + threadIdx.x;
    const int stride = gridDim.x * blockDim.x;

    float acc = 0.0f;
    for (int i = tid; i < nN; i += stride) {
        int p = i / CP;
        int off = i - p * CP;
        const float* base = scratch + ((size_t)p * Bpp + 0) * CP + off;

        float s0 = traffic[i], s1 = 0.0f, s2 = 0.0f, s3 = 0.0f;
        int b = 0;
        for (; b + 8 <= Bpp; b += 8) {
            const float* q = base + (size_t)b * CP;
            float a0 = q[0 * (size_t)CP];
            float a1 = q[1 * (size_t)CP];
            float a2 = q[2 * (size_t)CP];
            float a3 = q[3 * (size_t)CP];
            float a4 = q[4 * (size_t)CP];
            float a5 = q[5 * (size_t)CP];
            float a6 = q[6 * (size_t)CP];
            float a7 = q[7 * (size_t)CP];
            s0 += a0 + a4;
            s1 += a1 + a5;
            s2 += a2 + a6;
            s3 += a3 + a7;
        }
        for (; b < Bpp; ++b) s0 += base[(size_t)b * CP];
        float s = (s0 + s1) + (s2 + s3);
        out[i] = s;
        acc = fmaf(yield_rate[i], s, acc) - cost[i];
    }

    #pragma unroll
    for (int off = 32; off > 0; off >>= 1) acc += __shfl_down(acc, off, 64);

    __shared__ float wsum[4];
    const int lane = threadIdx.x & 63;
    const int wid = threadIdx.x >> 6;
    if (lane == 0) wsum[wid] = acc;
    __syncthreads();
    if (threadIdx.x == 0)
        atomicAdd(&out[nN], wsum[0] + wsum[1] + wsum[2] + wsum[3]);
}

// ---------------------------------------------------------------------------
// Fallback path (ws too small): direct-atomic version.
// ---------------------------------------------------------------------------
__global__ void init_out_kernel(const float* __restrict__ traffic,
                                float* __restrict__ out, int nN) {
    int i = blockIdx.x * blockDim.x + threadIdx.x;
    if (i < nN) out[i] = traffic[i];
    else if (i == nN) out[i] = 0.0f;
}

__global__ __launch_bounds__(256) void edge_scatter_kernel(
    const int* __restrict__ src_idx, const int* __restrict__ dst_idx,
    const float* __restrict__ w, const float* __restrict__ traffic,
    float* __restrict__ out, int nE) {
    const int tid = blockIdx.x * blockDim.x + threadIdx.x;
    const int stride = gridDim.x * blockDim.x;
    for (int e = tid; e < nE; e += stride) {
        int s = src_idx[e];
        int d = dst_idx[e];
        float t = fabsf(traffic[s] - traffic[d]) * (PENALTY_N * w[e]);
        atomicAdd(&out[s], -t);
        atomicAdd(&out[d], t);
    }
}

__global__ __launch_bounds__(256) void reduce_kernel(
    const float* __restrict__ new_traffic, const float* __restrict__ yield_rate,
    const float* __restrict__ cost, float* __restrict__ total, int nN) {
    const int tid = blockIdx.x * blockDim.x + threadIdx.x;
    const int stride = gridDim.x * blockDim.x;
    float acc = 0.0f;
    for (int i = tid; i < nN; i += stride)
        acc = fmaf(yield_rate[i], new_traffic[i], acc) - cost[i];
    #pragma unroll
    for (int off = 32; off > 0; off >>= 1) acc += __shfl_down(acc, off, 64);
    __shared__ float wsum[4];
    const int lane = threadIdx.x & 63;
    const int wid = threadIdx.x >> 6;
    if (lane == 0) wsum[wid] = acc;
    __syncthreads();
    if (threadIdx.x == 0)
        atomicAdd(total, wsum[0] + wsum[1] + wsum[2] + wsum[3]);
}

// ---------------------------------------------------------------------------
extern "C" void kernel_launch(void* const* d_in, const int* in_sizes, int n_in,
                              void* d_out, int out_size, void* d_ws, size_t ws_size,
                              hipStream_t stream) {
    const int* edge_index = (const int*)d_in[0];     // (2, E) flat
    const float* edge_weight = (const float*)d_in[1];
    const float* nodes_yield = (const float*)d_in[2];
    const float* nodes_traffic = (const float*)d_in[3];
    const float* nodes_cost = (const float*)d_in[4];
    float* out = (float*)d_out;

    const int nE = in_sizes[1];
    const int nN = in_sizes[2];
    const int* src_idx = edge_index;
    const int* dst_idx = edge_index + nE;

    const int P = (nN + CP - 1) / CP;   // 5 for nN=100K
    int Bpp = (int)(ws_size / ((size_t)P * CP * sizeof(float)));
    if (Bpp > MAX_BPP) Bpp = MAX_BPP;

    if (Bpp >= 4 && P <= 8) {
        float* scratch = (float*)d_ws;
        part_scatter_kernel<<<P * Bpp, ABLK, 0, stream>>>(
            src_idx, dst_idx, edge_weight, nodes_traffic,
            scratch, out + nN, nE, nN, Bpp);
        int rgrid = (nN + 255) / 256;
        part_reduce_kernel<<<rgrid, 256, 0, stream>>>(
            scratch, nodes_traffic, nodes_yield, nodes_cost, out, nN, Bpp);
    } else {
        int grid = (nN + 1 + 255) / 256;
        init_out_kernel<<<grid, 256, 0, stream>>>(nodes_traffic, out, nN);
        edge_scatter_kernel<<<2048, 256, 0, stream>>>(src_idx, dst_idx,
                                                      edge_weight, nodes_traffic,
                                                      out, nE);
        reduce_kernel<<<256, 256, 0, stream>>>(out, nodes_yield, nodes_cost,
                                               out + nN, nN);
    }
}

// Round 4
// 227.434 us; speedup vs baseline: 1.0084x; 1.0084x over previous
//
#include <hip/hip_runtime.h>

#define PENALTY_N 0.1f
#define CP 33344         // nodes per partition (mult of 64); P=3 covers 100,032
#define HPAD 64          // LDS pad; dump slot lives at index CP
#define MAX_BPP 85       // P*MAX_BPP = 255 blocks = 1/CU
#define ABLK 1024        // threads per block, partition kernel

// ---------------------------------------------------------------------------
// Kernel A: partitioned scatter with LDS privatization, P=3.
// Block = (partition p, edge-slice b).  hist[CP+HPAD] floats = 133.6 KB LDS
// -> 1 block/CU, 16 waves.  Measured regime is per-iteration issue-bound
// (~11 CU-cyc/vec4-iter regardless of occupancy), so we minimize total
// iterations (P=3) and per-iteration instructions:
//   - single branch per edge on (inS||inD)
//   - inside it, LDS atomics are unconditional via a dump slot at hist[CP]
// Flush = plain float4 stores to private scratch (no global atomics).
// ---------------------------------------------------------------------------
__global__ __launch_bounds__(ABLK, 4) void part_scatter_kernel(
    const int* __restrict__ src_idx,
    const int* __restrict__ dst_idx,
    const float* __restrict__ w,
    const float* __restrict__ traffic,
    float* __restrict__ scratch,   // [P][Bpp][CP]
    float* __restrict__ out_scalar,
    int nE, int nN, int Bpp) {
    __shared__ float hist[CP + HPAD];

    const int p = blockIdx.x / Bpp;    // partition
    const int b = blockIdx.x % Bpp;    // edge slice
    const int lo = p * CP;
    const unsigned csz = (unsigned)min(CP, nN - lo);
    const int tid = threadIdx.x;

    if (blockIdx.x == 0 && tid == 0) *out_scalar = 0.0f;

    // zero LDS (vectorized)
    {
        float4* h4 = (float4*)hist;
        const int n4 = (CP + HPAD) / 4;
        for (int i = tid; i < n4; i += ABLK)
            h4[i] = make_float4(0.f, 0.f, 0.f, 0.f);
    }
    __syncthreads();

    const int nvec = nE >> 2;
    const int4* __restrict__ src4 = (const int4*)src_idx;
    const int4* __restrict__ dst4 = (const int4*)dst_idx;
    const float4* __restrict__ w4 = (const float4*)w;
    const int stride = Bpp * ABLK;

    for (int v = b * ABLK + tid; v < nvec; v += stride) {
        int4 s = src4[v];
        int4 d = dst4[v];
        float4 ww = w4[v];

        #pragma unroll
        for (int k = 0; k < 4; ++k) {
            int si = (&s.x)[k];
            int di = (&d.x)[k];
            unsigned so = (unsigned)(si - lo);
            unsigned doo = (unsigned)(di - lo);
            bool inS = so < csz;
            bool inD = doo < csz;
            if (inS || inD) {
                float t = fabsf(traffic[si] - traffic[di]) * (PENALTY_N * (&ww.x)[k]);
                unsigned iS = inS ? so : (unsigned)CP;   // dump slot if OOR
                unsigned iD = inD ? doo : (unsigned)CP;
                atomicAdd(&hist[iS], -t);
                atomicAdd(&hist[iD], t);
            }
        }
    }
    // scalar tail (nE % 4 != 0)
    for (int e = (nvec << 2) + b * ABLK + tid; e < nE; e += stride) {
        int si = src_idx[e];
        int di = dst_idx[e];
        unsigned so = (unsigned)(si - lo);
        unsigned doo = (unsigned)(di - lo);
        bool inS = so < csz;
        bool inD = doo < csz;
        if (inS || inD) {
            float t = fabsf(traffic[si] - traffic[di]) * (PENALTY_N * w[e]);
            unsigned iS = inS ? so : (unsigned)CP;
            unsigned iD = inD ? doo : (unsigned)CP;
            atomicAdd(&hist[iS], -t);
            atomicAdd(&hist[iD], t);
        }
    }

    __syncthreads();
    // flush private histogram: float4 bulk + scalar tail (coalesced)
    float* dst = scratch + (size_t)blockIdx.x * CP;
    {
        const int n4 = (int)(csz >> 2);
        float4* d4 = (float4*)dst;
        const float4* h4 = (const float4*)hist;
        for (int i = tid; i < n4; i += ABLK) d4[i] = h4[i];
        for (int i = (n4 << 2) + tid; i < (int)csz; i += ABLK) dst[i] = hist[i];
    }
}

// ---------------------------------------------------------------------------
// Kernel B: per-node sum of the Bpp private copies + base traffic; writes
// new_traffic and fuses the service-efficiency reduction.
// 8 independent loads in flight to break the latency chain.
// ---------------------------------------------------------------------------
__global__ __launch_bounds__(256) void part_reduce_kernel(
    const float* __restrict__ scratch,
    const float* __restrict__ traffic,
    const float* __restrict__ yield_rate,
    const float* __restrict__ cost,
    float* __restrict__ out,        // [nN] new_traffic, out[nN] scalar
    int nN, int Bpp) {
    const int tid = blockIdx.x * blockDim.x + threadIdx.x;
    const int stride = gridDim.x * blockDim.x;

    float acc = 0.0f;
    for (int i = tid; i < nN; i += stride) {
        int p = i / CP;
        int off = i - p * CP;
        const float* base = scratch + (size_t)p * Bpp * CP + off;

        float s0 = traffic[i], s1 = 0.0f, s2 = 0.0f, s3 = 0.0f;
        int b = 0;
        for (; b + 8 <= Bpp; b += 8) {
            const float* q = base + (size_t)b * CP;
            float a0 = q[0 * (size_t)CP];
            float a1 = q[1 * (size_t)CP];
            float a2 = q[2 * (size_t)CP];
            float a3 = q[3 * (size_t)CP];
            float a4 = q[4 * (size_t)CP];
            float a5 = q[5 * (size_t)CP];
            float a6 = q[6 * (size_t)CP];
            float a7 = q[7 * (size_t)CP];
            s0 += a0 + a4;
            s1 += a1 + a5;
            s2 += a2 + a6;
            s3 += a3 + a7;
        }
        for (; b < Bpp; ++b) s0 += base[(size_t)b * CP];
        float s = (s0 + s1) + (s2 + s3);
        out[i] = s;
        acc = fmaf(yield_rate[i], s, acc) - cost[i];
    }

    #pragma unroll
    for (int off = 32; off > 0; off >>= 1) acc += __shfl_down(acc, off, 64);

    __shared__ float wsum[4];
    const int lane = threadIdx.x & 63;
    const int wid = threadIdx.x >> 6;
    if (lane == 0) wsum[wid] = acc;
    __syncthreads();
    if (threadIdx.x == 0)
        atomicAdd(&out[nN], wsum[0] + wsum[1] + wsum[2] + wsum[3]);
}

// ---------------------------------------------------------------------------
// Fallback path (ws too small): direct-atomic version.
// ---------------------------------------------------------------------------
__global__ void init_out_kernel(const float* __restrict__ traffic,
                                float* __restrict__ out, int nN) {
    int i = blockIdx.x * blockDim.x + threadIdx.x;
    if (i < nN) out[i] = traffic[i];
    else if (i == nN) out[i] = 0.0f;
}

__global__ __launch_bounds__(256) void edge_scatter_kernel(
    const int* __restrict__ src_idx, const int* __restrict__ dst_idx,
    const float* __restrict__ w, const float* __restrict__ traffic,
    float* __restrict__ out, int nE) {
    const int tid = blockIdx.x * blockDim.x + threadIdx.x;
    const int stride = gridDim.x * blockDim.x;
    for (int e = tid; e < nE; e += stride) {
        int s = src_idx[e];
        int d = dst_idx[e];
        float t = fabsf(traffic[s] - traffic[d]) * (PENALTY_N * w[e]);
        atomicAdd(&out[s], -t);
        atomicAdd(&out[d], t);
    }
}

__global__ __launch_bounds__(256) void reduce_kernel(
    const float* __restrict__ new_traffic, const float* __restrict__ yield_rate,
    const float* __restrict__ cost, float* __restrict__ total, int nN) {
    const int tid = blockIdx.x * blockDim.x + threadIdx.x;
    const int stride = gridDim.x * blockDim.x;
    float acc = 0.0f;
    for (int i = tid; i < nN; i += stride)
        acc = fmaf(yield_rate[i], new_traffic[i], acc) - cost[i];
    #pragma unroll
    for (int off = 32; off > 0; off >>= 1) acc += __shfl_down(acc, off, 64);
    __shared__ float wsum[4];
    const int lane = threadIdx.x & 63;
    const int wid = threadIdx.x >> 6;
    if (lane == 0) wsum[wid] = acc;
    __syncthreads();
    if (threadIdx.x == 0)
        atomicAdd(total, wsum[0] + wsum[1] + wsum[2] + wsum[3]);
}

// ---------------------------------------------------------------------------
extern "C" void kernel_launch(void* const* d_in, const int* in_sizes, int n_in,
                              void* d_out, int out_size, void* d_ws, size_t ws_size,
                              hipStream_t stream) {
    const int* edge_index = (const int*)d_in[0];     // (2, E) flat
    const float* edge_weight = (const float*)d_in[1];
    const float* nodes_yield = (const float*)d_in[2];
    const float* nodes_traffic = (const float*)d_in[3];
    const float* nodes_cost = (const float*)d_in[4];
    float* out = (float*)d_out;

    const int nE = in_sizes[1];
    const int nN = in_sizes[2];
    const int* src_idx = edge_index;
    const int* dst_idx = edge_index + nE;

    const int P = (nN + CP - 1) / CP;   // 3 for nN=100K
    int Bpp = (int)(ws_size / ((size_t)P * CP * sizeof(float)));
    if (Bpp > MAX_BPP) Bpp = MAX_BPP;

    if (Bpp >= 4 && P <= 8) {
        float* scratch = (float*)d_ws;
        part_scatter_kernel<<<P * Bpp, ABLK, 0, stream>>>(
            src_idx, dst_idx, edge_weight, nodes_traffic,
            scratch, out + nN, nE, nN, Bpp);
        int rgrid = (nN + 255) / 256;
        part_reduce_kernel<<<rgrid, 256, 0, stream>>>(
            scratch, nodes_traffic, nodes_yield, nodes_cost, out, nN, Bpp);
    } else {
        int grid = (nN + 1 + 255) / 256;
        init_out_kernel<<<grid, 256, 0, stream>>>(nodes_traffic, out, nN);
        edge_scatter_kernel<<<2048, 256, 0, stream>>>(src_idx, dst_idx,
                                                      edge_weight, nodes_traffic,
                                                      out, nE);
        reduce_kernel<<<256, 256, 0, stream>>>(out, nodes_yield, nodes_cost,
                                               out + nN, nN);
    }
}